// Round 13
// baseline (1093.733 us; speedup 1.0000x reference)
//
#include <hip/hip_runtime.h>
#include <math.h>

#define NROWS 8192
#define DIM   64
#define KSEL  32
#define NQ    (NROWS - KSEL)   /* 8160 query rows */
#define P1LEN 512              /* pass-1 exact prefix */
#define CAP   1024             /* per-query candidate list capacity */
#define QT    64               /* queries per pass2 block (one wave-width) */
#define WCH   256              /* candidates per pass2 wave */
#define BCH   1024             /* candidates per pass2 block (4 waves) */

// ---------------------------------------------------------------------------
// Kernel A: row norms replicating XLA:CPU (LLVM-vectorized fused reduce):
//   VF=8 lanes, init 0, per-lane FMA chain, horizontal shuffle-tree
//   ((r0+r4)+(r2+r6)) + ((r1+r5)+(r3+r7)).   [validated bit-exact R8-R12]
// ---------------------------------------------------------------------------
__global__ void norms_kernel(const float* __restrict__ x, float* __restrict__ sq) {
    int j = blockIdx.x * blockDim.x + threadIdx.x;
    if (j >= NROWS) return;
    const float* xr = x + (size_t)j * DIM;
    float r[8];
#pragma unroll
    for (int u = 0; u < 8; ++u) r[u] = 0.0f;
#pragma unroll
    for (int i = 0; i < DIM; i += 8) {
#pragma unroll
        for (int u = 0; u < 8; ++u)
            r[u] = __fmaf_rn(xr[i + u], xr[i + u], r[u]);
    }
    const float s04 = __fadd_rn(r[0], r[4]);
    const float s26 = __fadd_rn(r[2], r[6]);
    const float s15 = __fadd_rn(r[1], r[5]);
    const float s37 = __fadd_rn(r[3], r[7]);
    sq[j] = __fadd_rn(__fadd_rn(s04, s26), __fadd_rn(s15, s37));
}

// ---------------------------------------------------------------------------
// Pass 1: ONE WAVE per query.  Exact top-32 over prefix [0, min(512, r)):
// 8 keys/lane in registers, 32 shuffle-only extract-min iterations
// (no LDS, no barriers).  Writes the 32 keys to lists[qi][0..31],
// cnt[qi]=32, tau0[qi]=32nd-smallest key (safe bound for the filter).
// Distance = bit-exact seq-FMA chain k=0..63 (validated).
// ---------------------------------------------------------------------------
__global__ __launch_bounds__(64)
void pass1_kernel(const float* __restrict__ x, const float* __restrict__ sq,
                  unsigned long long* __restrict__ tau0,
                  unsigned int* __restrict__ cnt,
                  unsigned long long* __restrict__ lists) {
    const int qi   = blockIdx.x;        // 0..8159
    const int r    = qi + KSEL;         // query row (wave-uniform)
    const int lane = threadIdx.x;
    const int P    = min(r, P1LEN);

    const float* qp  = x + (size_t)r * DIM;   // uniform -> scalar loads
    const float  sqr = sq[r];

    unsigned long long key[8];
#pragma unroll
    for (int s = 0; s < 8; ++s) {
        const int j = lane + (s << 6);
        unsigned long long k = ~0ull;
        if (j < P) {
            const float4* c4 = reinterpret_cast<const float4*>(x + (size_t)j * DIM);
            float acc = 0.0f;
#pragma unroll
            for (int i = 0; i < DIM / 4; ++i) {
                float4 v = c4[i];
                acc = __fmaf_rn(qp[4 * i + 0], v.x, acc);
                acc = __fmaf_rn(qp[4 * i + 1], v.y, acc);
                acc = __fmaf_rn(qp[4 * i + 2], v.z, acc);
                acc = __fmaf_rn(qp[4 * i + 3], v.w, acc);
            }
            const float dd =
                fmaxf(__fsub_rn(__fadd_rn(sqr, sq[j]), __fmul_rn(2.0f, acc)), 0.0f);
            k = ((unsigned long long)__float_as_uint(dd) << 32) | (unsigned)j;
        }
        key[s] = k;
    }

    unsigned long long pmin = ~0ull;
#pragma unroll
    for (int s = 0; s < 8; ++s) pmin = key[s] < pmin ? key[s] : pmin;

    unsigned long long g = ~0ull;
    for (int it = 0; it < KSEL; ++it) {
        unsigned long long v = pmin;
#pragma unroll
        for (int off = 32; off > 0; off >>= 1) {
            const unsigned long long o = __shfl_down(v, off, 64);
            v = o < v ? o : v;
        }
        g = __shfl(v, 0, 64);
        if (lane == 0) lists[(size_t)qi * CAP + it] = g;
        if (pmin == g) {            // unique winner (keys embed unique j)
#pragma unroll
            for (int s = 0; s < 8; ++s) if (key[s] == g) key[s] = ~0ull;
            pmin = ~0ull;
#pragma unroll
            for (int s = 0; s < 8; ++s) pmin = key[s] < pmin ? key[s] : pmin;
        }
    }
    if (lane == 0) { tau0[qi] = g; cnt[qi] = KSEL; }
}

// ---------------------------------------------------------------------------
// Pass 2: filter candidates [512, r) against tau0.  Block = 256 threads
// (4 waves) sharing one 64-query tile staged TRANSPOSED in LDS
// (Q[d][lane], 16 KB, stride-1 conflict-free) -- the per-lane query operand
// is a ds_read, never scratch.  Candidates are wave-uniform (scalar loads).
// ILP-8 bit-exact seq-FMA chains.  Accept: float-bits(d) <= tau_hi
// (safe superset; merge resolves exactly).  Append via atomicAdd.
// ---------------------------------------------------------------------------
__global__ __launch_bounds__(256)
void pass2_kernel(const float* __restrict__ x, const float* __restrict__ sq,
                  const unsigned long long* __restrict__ tau0,
                  unsigned int* __restrict__ cnt,
                  unsigned long long* __restrict__ lists) {
    const int qb   = blockIdx.x;                      // 0..127
    const int r_hi = min(KSEL + (qb + 1) * QT, NROWS);
    const int bbeg = blockIdx.y * BCH;
    if (bbeg >= r_hi) return;          // uniform block exit (before barrier)

    const int tid  = threadIdx.x;
    const int wave = tid >> 6;
    const int lane = tid & 63;

    __shared__ float Q[DIM * QT];                     // Q[d*64 + l], 16 KB

    {   // stage 64 query rows transposed (rows clamped; extras unused)
        const int l    = tid >> 2;                    // 0..63
        const int cb   = (tid & 3) * 16;              // col base
        const int qrow = min(KSEL + qb * QT + l, NROWS - 1);
        const float4* src =
            reinterpret_cast<const float4*>(x + (size_t)qrow * DIM + cb);
#pragma unroll
        for (int i = 0; i < 4; ++i) {
            float4 v = src[i];
            const int c = cb + i * 4;
            Q[(c + 0) * QT + l] = v.x;
            Q[(c + 1) * QT + l] = v.y;
            Q[(c + 2) * QT + l] = v.z;
            Q[(c + 3) * QT + l] = v.w;
        }
    }
    __syncthreads();

    const int  r_raw = KSEL + qb * QT + lane;
    const bool vq    = (r_raw < NROWS);
    const int  r     = vq ? r_raw : 0;                // r=0 => never accepts
    const int  qi    = vq ? (r_raw - KSEL) : 0;
    const float sqr  = vq ? sq[r_raw] : 0.0f;
    const unsigned tau_hi = vq ? (unsigned)(tau0[qi] >> 32) : 0u;

    int wbeg = bbeg + wave * WCH;
    const int wend = min(wbeg + WCH, r_hi);
    wbeg = max(wbeg, P1LEN);           // prefix handled exactly by pass1

    for (int j0 = wbeg; j0 < wend; j0 += 8) {
        const float* c0 = x + (size_t)j0 * DIM;       // uniform -> scalar loads
        float a0 = 0.f, a1 = 0.f, a2 = 0.f, a3 = 0.f;
        float a4 = 0.f, a5 = 0.f, a6 = 0.f, a7 = 0.f;
#pragma unroll
        for (int d = 0; d < DIM; ++d) {               // bit-exact seq chains
            const float qd = Q[d * QT + lane];        // ds_read_b32, imm offset
            a0 = __fmaf_rn(qd, c0[d], a0);
            a1 = __fmaf_rn(qd, c0[d + DIM], a1);
            a2 = __fmaf_rn(qd, c0[d + 2 * DIM], a2);
            a3 = __fmaf_rn(qd, c0[d + 3 * DIM], a3);
            a4 = __fmaf_rn(qd, c0[d + 4 * DIM], a4);
            a5 = __fmaf_rn(qd, c0[d + 5 * DIM], a5);
            a6 = __fmaf_rn(qd, c0[d + 6 * DIM], a6);
            a7 = __fmaf_rn(qd, c0[d + 7 * DIM], a7);
        }
        float acc[8] = {a0, a1, a2, a3, a4, a5, a6, a7};
#pragma unroll
        for (int u = 0; u < 8; ++u) {
            const int j = j0 + u;
            const float dd = fmaxf(
                __fsub_rn(__fadd_rn(sqr, sq[j]), __fmul_rn(2.0f, acc[u])), 0.0f);
            const unsigned bits = __float_as_uint(dd);
            if (j < r && bits <= tau_hi) {
                const unsigned s = atomicAdd(&cnt[qi], 1u);
                if (s < CAP)
                    lists[(size_t)qi * CAP + s] =
                        ((unsigned long long)bits << 32) | (unsigned)j;
            }
        }
    }
}

// ---------------------------------------------------------------------------
// Merge: ONE WAVE per query.  16 keys/lane in registers, 32 shuffle-only
// extract-min iterations.  u64-min = ascending (dist, index), low-index
// ties (validated top_k semantics).  List is a superset of the true top-32.
// ---------------------------------------------------------------------------
__global__ __launch_bounds__(64)
void merge_kernel(const unsigned long long* __restrict__ lists,
                  const unsigned int* __restrict__ cnt,
                  float* __restrict__ out_d, float* __restrict__ out_i) {
    const int qi   = blockIdx.x;     // 0..8159
    const int lane = threadIdx.x;
    const int ne   = min((int)cnt[qi], CAP);
    const unsigned long long* src = lists + (size_t)qi * CAP;

    unsigned long long k[16];
#pragma unroll
    for (int s = 0; s < 16; ++s) {
        const int idx = lane + (s << 6);
        k[s] = (idx < ne) ? src[idx] : ~0ull;
    }
    unsigned long long pmin = ~0ull;
#pragma unroll
    for (int s = 0; s < 16; ++s) pmin = k[s] < pmin ? k[s] : pmin;

    for (int it = 0; it < KSEL; ++it) {
        unsigned long long v = pmin;
#pragma unroll
        for (int off = 32; off > 0; off >>= 1) {
            const unsigned long long o = __shfl_down(v, off, 64);
            v = o < v ? o : v;
        }
        const unsigned long long g = __shfl(v, 0, 64);
        if (lane == 0) {
            out_d[(size_t)qi * KSEL + it] = __uint_as_float((unsigned)(g >> 32));
            out_i[(size_t)qi * KSEL + it] = (float)(unsigned)(g & 0xFFFFFFFFu);
        }
        if (pmin == g) {            // unique winner rescans its registers
#pragma unroll
            for (int s = 0; s < 16; ++s) if (k[s] == g) k[s] = ~0ull;
            pmin = ~0ull;
#pragma unroll
            for (int s = 0; s < 16; ++s) pmin = k[s] < pmin ? k[s] : pmin;
        }
    }
}

extern "C" void kernel_launch(void* const* d_in, const int* in_sizes, int n_in,
                              void* d_out, int out_size, void* d_ws, size_t ws_size,
                              hipStream_t stream) {
    const float* x = (const float*)d_in[0];    // anchor_x [8192, 64] fp32
    float* sq = (float*)d_ws;                                        // 32 KB
    unsigned long long* tau0 =
        (unsigned long long*)((char*)d_ws + 32768);                  // 64 KB
    unsigned int* cnt = (unsigned int*)((char*)d_ws + 98304);        // 32 KB
    unsigned long long* lists =
        (unsigned long long*)((char*)d_ws + 131072);                 // 66.8 MB
    float* out_d = (float*)d_out;              // [8160, 32] distances
    float* out_i = out_d + (size_t)NQ * KSEL;  // [8160, 32] indices (as fp32)

    norms_kernel<<<NROWS / 256, 256, 0, stream>>>(x, sq);
    pass1_kernel<<<NQ, 64, 0, stream>>>(x, sq, tau0, cnt, lists);
    dim3 g2(128, NROWS / BCH);                 // (qb, candidate block)
    pass2_kernel<<<g2, 256, 0, stream>>>(x, sq, tau0, cnt, lists);
    merge_kernel<<<NQ, 64, 0, stream>>>(lists, cnt, out_d, out_i);
}

// Round 14
// 397.918 us; speedup vs baseline: 2.7486x; 2.7486x over previous
//
#include <hip/hip_runtime.h>
#include <math.h>

#define NROWS 8192
#define DIM   64
#define KSEL  32
#define NQ    (NROWS - KSEL)   /* 8160 query rows */
#define P1LEN 512              /* pass-1 exact prefix */
#define CAP   1024             /* per-query candidate list capacity */

// ---------------------------------------------------------------------------
// Kernel A: row norms replicating XLA:CPU (LLVM-vectorized fused reduce):
//   VF=8 lanes, init 0, per-lane FMA chain, horizontal shuffle-tree
//   ((r0+r4)+(r2+r6)) + ((r1+r5)+(r3+r7)).   [validated bit-exact R8-R13]
// ---------------------------------------------------------------------------
__global__ void norms_kernel(const float* __restrict__ x, float* __restrict__ sq) {
    int j = blockIdx.x * blockDim.x + threadIdx.x;
    if (j >= NROWS) return;
    const float* xr = x + (size_t)j * DIM;
    float r[8];
#pragma unroll
    for (int u = 0; u < 8; ++u) r[u] = 0.0f;
#pragma unroll
    for (int i = 0; i < DIM; i += 8) {
#pragma unroll
        for (int u = 0; u < 8; ++u)
            r[u] = __fmaf_rn(xr[i + u], xr[i + u], r[u]);
    }
    const float s04 = __fadd_rn(r[0], r[4]);
    const float s26 = __fadd_rn(r[2], r[6]);
    const float s15 = __fadd_rn(r[1], r[5]);
    const float s37 = __fadd_rn(r[3], r[7]);
    sq[j] = __fadd_rn(__fadd_rn(s04, s26), __fadd_rn(s15, s37));
}

// ---------------------------------------------------------------------------
// Pass 1: ONE WAVE per query.  Exact top-32 over prefix [0, min(512, r)):
// 8 keys/lane in registers, 32 shuffle-only extract-min iterations.
// Writes the 32 keys to lists[qi][0..31], cnt[qi]=32, tau0[qi]=32nd key.
// Distance = bit-exact seq-FMA chain k=0..63 (validated).
// ---------------------------------------------------------------------------
__global__ __launch_bounds__(64)
void pass1_kernel(const float* __restrict__ x, const float* __restrict__ sq,
                  unsigned long long* __restrict__ tau0,
                  unsigned int* __restrict__ cnt,
                  unsigned long long* __restrict__ lists) {
    const int qi   = blockIdx.x;        // 0..8159
    const int r    = qi + KSEL;         // query row (wave-uniform)
    const int lane = threadIdx.x;
    const int P    = min(r, P1LEN);

    const float* qp  = x + (size_t)r * DIM;   // uniform -> scalar loads
    const float  sqr = sq[r];

    unsigned long long key[8];
#pragma unroll
    for (int s = 0; s < 8; ++s) {
        const int j = lane + (s << 6);
        unsigned long long k = ~0ull;
        if (j < P) {
            const float4* c4 = reinterpret_cast<const float4*>(x + (size_t)j * DIM);
            float acc = 0.0f;
#pragma unroll
            for (int i = 0; i < DIM / 4; ++i) {
                float4 v = c4[i];
                acc = __fmaf_rn(qp[4 * i + 0], v.x, acc);
                acc = __fmaf_rn(qp[4 * i + 1], v.y, acc);
                acc = __fmaf_rn(qp[4 * i + 2], v.z, acc);
                acc = __fmaf_rn(qp[4 * i + 3], v.w, acc);
            }
            const float dd =
                fmaxf(__fsub_rn(__fadd_rn(sqr, sq[j]), __fmul_rn(2.0f, acc)), 0.0f);
            k = ((unsigned long long)__float_as_uint(dd) << 32) | (unsigned)j;
        }
        key[s] = k;
    }

    unsigned long long pmin = ~0ull;
#pragma unroll
    for (int s = 0; s < 8; ++s) pmin = key[s] < pmin ? key[s] : pmin;

    unsigned long long g = ~0ull;
    for (int it = 0; it < KSEL; ++it) {
        unsigned long long v = pmin;
#pragma unroll
        for (int off = 32; off > 0; off >>= 1) {
            const unsigned long long o = __shfl_down(v, off, 64);
            v = o < v ? o : v;
        }
        g = __shfl(v, 0, 64);
        if (lane == 0) lists[(size_t)qi * CAP + it] = g;
        if (pmin == g) {            // unique winner (keys embed unique j)
#pragma unroll
            for (int s = 0; s < 8; ++s) if (key[s] == g) key[s] = ~0ull;
            pmin = ~0ull;
#pragma unroll
            for (int s = 0; s < 8; ++s) pmin = key[s] < pmin ? key[s] : pmin;
        }
    }
    if (lane == 0) { tau0[qi] = g; cnt[qi] = KSEL; }
}

// ---------------------------------------------------------------------------
// Pass 2: LDS-tiled fp32 GEMM filter over candidates [512, r).
// Tile = 64 queries x 64 candidates.  Both tiles staged TRANSPOSED in LDS
// (Qs[k][q], Cs[k][c]) so the hot loop is 2x aligned ds_read_b128 + 16 FMA
// per k-step.  Each accumulator = single fp32 FMA chain over k=0..63
// ascending == the validated bit-exact Eigen chain.  Epilogue: accept
// bits(dist) <= tau_hi (safe superset), append via atomicAdd.
// ---------------------------------------------------------------------------
__global__ __launch_bounds__(256)
void pass2_kernel(const float* __restrict__ x, const float* __restrict__ sq,
                  const unsigned long long* __restrict__ tau0,
                  unsigned int* __restrict__ cnt,
                  unsigned long long* __restrict__ lists) {
    const int qb   = blockIdx.x;                       // 0..127
    const int jb   = P1LEN + blockIdx.y * 64;          // candidate tile base
    const int r_hi = min(KSEL + (qb + 1) * 64, NROWS); // exclusive query cap
    if (jb >= r_hi) return;                            // uniform exit

    __shared__ float Qs[DIM * 64];                     // Qs[k*64 + ql]
    __shared__ float Cs[DIM * 64];                     // Cs[k*64 + cl]
    __shared__ float sqq[64], sqc[64];
    __shared__ unsigned tauh[64];

    const int tid = threadIdx.x;

    {   // stage both tiles transposed (4-way write conflicts, staging only)
        const int row = tid >> 2;                      // 0..63
        const int db  = (tid & 3) * 16;                // dim base
        const int rq  = min(KSEL + qb * 64 + row, NROWS - 1);
        const float4* sQ = reinterpret_cast<const float4*>(x + (size_t)rq * DIM + db);
        const float4* sC = reinterpret_cast<const float4*>(x + (size_t)(jb + row) * DIM + db);
#pragma unroll
        for (int i = 0; i < 4; ++i) {
            float4 v = sQ[i];
            const int d = db + i * 4;
            Qs[(d + 0) * 64 + row] = v.x; Qs[(d + 1) * 64 + row] = v.y;
            Qs[(d + 2) * 64 + row] = v.z; Qs[(d + 3) * 64 + row] = v.w;
            float4 w = sC[i];
            Cs[(d + 0) * 64 + row] = w.x; Cs[(d + 1) * 64 + row] = w.y;
            Cs[(d + 2) * 64 + row] = w.z; Cs[(d + 3) * 64 + row] = w.w;
        }
    }
    if (tid < 64) {
        const int rq = KSEL + qb * 64 + tid;
        const bool v = (rq < NROWS);
        sqq[tid]  = v ? sq[rq] : 0.0f;
        tauh[tid] = v ? (unsigned)(tau0[rq - KSEL] >> 32) : 0u;
        sqc[tid]  = sq[jb + tid];
    }
    __syncthreads();

    const int tx = tid & 15;        // candidate group (4 cols)
    const int ty = tid >> 4;        // query group (4 rows)

    float acc[4][4] = {{0.f}};      // acc[qy][cx], chains over k ascending
#pragma unroll 8
    for (int k = 0; k < DIM; ++k) {
        const float4 aq = *reinterpret_cast<const float4*>(&Qs[k * 64 + ty * 4]);
        const float4 ac = *reinterpret_cast<const float4*>(&Cs[k * 64 + tx * 4]);
        acc[0][0] = __fmaf_rn(aq.x, ac.x, acc[0][0]);
        acc[0][1] = __fmaf_rn(aq.x, ac.y, acc[0][1]);
        acc[0][2] = __fmaf_rn(aq.x, ac.z, acc[0][2]);
        acc[0][3] = __fmaf_rn(aq.x, ac.w, acc[0][3]);
        acc[1][0] = __fmaf_rn(aq.y, ac.x, acc[1][0]);
        acc[1][1] = __fmaf_rn(aq.y, ac.y, acc[1][1]);
        acc[1][2] = __fmaf_rn(aq.y, ac.z, acc[1][2]);
        acc[1][3] = __fmaf_rn(aq.y, ac.w, acc[1][3]);
        acc[2][0] = __fmaf_rn(aq.z, ac.x, acc[2][0]);
        acc[2][1] = __fmaf_rn(aq.z, ac.y, acc[2][1]);
        acc[2][2] = __fmaf_rn(aq.z, ac.z, acc[2][2]);
        acc[2][3] = __fmaf_rn(aq.z, ac.w, acc[2][3]);
        acc[3][0] = __fmaf_rn(aq.w, ac.x, acc[3][0]);
        acc[3][1] = __fmaf_rn(aq.w, ac.y, acc[3][1]);
        acc[3][2] = __fmaf_rn(aq.w, ac.z, acc[3][2]);
        acc[3][3] = __fmaf_rn(aq.w, ac.w, acc[3][3]);
    }

#pragma unroll
    for (int qy = 0; qy < 4; ++qy) {
        const int ql = ty * 4 + qy;
        const int rq = KSEL + qb * 64 + ql;
        if (rq >= NROWS) continue;
        const float sqr = sqq[ql];
        const unsigned th = tauh[ql];
        const int qi = rq - KSEL;
#pragma unroll
        for (int cx = 0; cx < 4; ++cx) {
            const int j = jb + tx * 4 + cx;
            const float dd = fmaxf(
                __fsub_rn(__fadd_rn(sqr, sqc[tx * 4 + cx]),
                          __fmul_rn(2.0f, acc[qy][cx])), 0.0f);
            const unsigned bits = __float_as_uint(dd);
            if (j < rq && bits <= th) {
                const unsigned s = atomicAdd(&cnt[qi], 1u);
                if (s < CAP)
                    lists[(size_t)qi * CAP + s] =
                        ((unsigned long long)bits << 32) | (unsigned)j;
            }
        }
    }
}

// ---------------------------------------------------------------------------
// Merge: ONE WAVE per query.  16 keys/lane in registers, 32 shuffle-only
// extract-min iterations.  u64-min = ascending (dist, index), low-index
// ties (validated top_k semantics).  List is a superset of the true top-32.
// ---------------------------------------------------------------------------
__global__ __launch_bounds__(64)
void merge_kernel(const unsigned long long* __restrict__ lists,
                  const unsigned int* __restrict__ cnt,
                  float* __restrict__ out_d, float* __restrict__ out_i) {
    const int qi   = blockIdx.x;     // 0..8159
    const int lane = threadIdx.x;
    const int ne   = min((int)cnt[qi], CAP);
    const unsigned long long* src = lists + (size_t)qi * CAP;

    unsigned long long k[16];
#pragma unroll
    for (int s = 0; s < 16; ++s) {
        const int idx = lane + (s << 6);
        k[s] = (idx < ne) ? src[idx] : ~0ull;
    }
    unsigned long long pmin = ~0ull;
#pragma unroll
    for (int s = 0; s < 16; ++s) pmin = k[s] < pmin ? k[s] : pmin;

    for (int it = 0; it < KSEL; ++it) {
        unsigned long long v = pmin;
#pragma unroll
        for (int off = 32; off > 0; off >>= 1) {
            const unsigned long long o = __shfl_down(v, off, 64);
            v = o < v ? o : v;
        }
        const unsigned long long g = __shfl(v, 0, 64);
        if (lane == 0) {
            out_d[(size_t)qi * KSEL + it] = __uint_as_float((unsigned)(g >> 32));
            out_i[(size_t)qi * KSEL + it] = (float)(unsigned)(g & 0xFFFFFFFFu);
        }
        if (pmin == g) {            // unique winner rescans its registers
#pragma unroll
            for (int s = 0; s < 16; ++s) if (k[s] == g) k[s] = ~0ull;
            pmin = ~0ull;
#pragma unroll
            for (int s = 0; s < 16; ++s) pmin = k[s] < pmin ? k[s] : pmin;
        }
    }
}

extern "C" void kernel_launch(void* const* d_in, const int* in_sizes, int n_in,
                              void* d_out, int out_size, void* d_ws, size_t ws_size,
                              hipStream_t stream) {
    const float* x = (const float*)d_in[0];    // anchor_x [8192, 64] fp32
    float* sq = (float*)d_ws;                                        // 32 KB
    unsigned long long* tau0 =
        (unsigned long long*)((char*)d_ws + 32768);                  // 64 KB
    unsigned int* cnt = (unsigned int*)((char*)d_ws + 98304);        // 32 KB
    unsigned long long* lists =
        (unsigned long long*)((char*)d_ws + 131072);                 // 66.8 MB
    float* out_d = (float*)d_out;              // [8160, 32] distances
    float* out_i = out_d + (size_t)NQ * KSEL;  // [8160, 32] indices (as fp32)

    norms_kernel<<<NROWS / 256, 256, 0, stream>>>(x, sq);
    pass1_kernel<<<NQ, 64, 0, stream>>>(x, sq, tau0, cnt, lists);
    dim3 g2(128, (NROWS - P1LEN) / 64);        // (query tile, candidate tile)
    pass2_kernel<<<g2, 256, 0, stream>>>(x, sq, tau0, cnt, lists);
    merge_kernel<<<NQ, 64, 0, stream>>>(lists, cnt, out_d, out_i);
}